// Round 6
// baseline (1753.024 us; speedup 1.0000x reference)
//
#include <hip/hip_runtime.h>

#define VV 50257
#define DD 50
#define TT 1024
#define BB 1024

__device__ __forceinline__ float rl(float v, int lane) {
    return __int_as_float(__builtin_amdgcn_readlane(__float_as_int(v), lane));
}
__device__ __forceinline__ float sigmf(float x) { return 1.0f / (1.0f + __expf(-x)); }
__device__ __forceinline__ float tanhf_fast(float x) {
    float e = __expf(-2.0f * fabsf(x));
    return copysignf((1.0f - e) / (1.0f + e), x);
}

// P1[v][j] = b1[0][j] + sum_d emb[v][d] * kx1[d][j]   (one-time, ~0.5 GFLOP)
__global__ void proj_emb(const float* __restrict__ emb, const float* __restrict__ kx1,
                         const float* __restrict__ b1, float* __restrict__ P1) {
    int j = threadIdx.x;             // 0..95
    int v0 = blockIdx.x * 8;
    #pragma unroll 1
    for (int vv = 0; vv < 8; ++vv) {
        int v = v0 + vv;
        if (v >= VV) return;
        float acc = b1[j];
        #pragma unroll
        for (int d = 0; d < DD; ++d)
            acc += emb[v * DD + d] * kx1[d * 96 + j];
        P1[v * 96 + j] = acc;
    }
}

// ---- macro-expanded register file: 192 named scalars, no arrays ----
#define R64(M) M(0) M(1) M(2) M(3) M(4) M(5) M(6) M(7) M(8) M(9) M(10) M(11) \
  M(12) M(13) M(14) M(15) M(16) M(17) M(18) M(19) M(20) M(21) M(22) M(23) \
  M(24) M(25) M(26) M(27) M(28) M(29) M(30) M(31) M(32) M(33) M(34) M(35) \
  M(36) M(37) M(38) M(39) M(40) M(41) M(42) M(43) M(44) M(45) M(46) M(47) \
  M(48) M(49) M(50) M(51) M(52) M(53) M(54) M(55) M(56) M(57) M(58) M(59) \
  M(60) M(61) M(62) M(63)
#define R32P(M) M(0,32) M(1,33) M(2,34) M(3,35) M(4,36) M(5,37) M(6,38) M(7,39) \
  M(8,40) M(9,41) M(10,42) M(11,43) M(12,44) M(13,45) M(14,46) M(15,47) \
  M(16,48) M(17,49) M(18,50) M(19,51) M(20,52) M(21,53) M(22,54) M(23,55) \
  M(24,56) M(25,57) M(26,58) M(27,59) M(28,60) M(29,61) M(30,62) M(31,63)

// Two waves per block, ONE row per block, one barrier per step (round-5
// structure, verified absmax 0).  The ONLY change vs round 5: the unified
// w[192] array is replaced by 192 named scalars with hand-expanded load/FMA
// chains.  Rationale (counters r3/r5): with the array, the compiler emitted
// ~1130 VALU instr per row-step vs ~530 needed and allocated only 116 arch
// VGPRs for a ~235-float live set — array-driven AGPR-split/copy bloat.
// Named scalars force SROA: each weight is one v_fma operand per step.
//  Wave A (wv=0): GRU2 recurrence. Pre-barrier: m(t)=h2(t-1)·kh2+b2[1].
//    Post-barrier: read x(t) from ring slot t&3, gates -> h2(t).
//  Wave B (wv=1): GRU1 + input projection, one step ahead. Pre-barrier:
//    prefetch P1(t+2), GRU1 recurrence+gates -> h1(t+1). Post-barrier:
//    x(t+1)=h1(t+1)·kx2+b2[0] -> ring slot (t+1)&3.
//  Ring safety: slot s written post-barrier of iter s-1, read post-barrier of
//  iter s (separated by barrier s), rewritten at iter s+3.
__global__ __launch_bounds__(128, 1)
void rnn_main(const int* __restrict__ tokens, const float* __restrict__ P1,
              const float* __restrict__ kh1, const float* __restrict__ b1,
              const float* __restrict__ kx2, const float* __restrict__ kh2,
              const float* __restrict__ b2, const float* __restrict__ wg,
              const float* __restrict__ bg, const float* __restrict__ wd,
              const float* __restrict__ bd, float* __restrict__ out) {
    const int lane = threadIdx.x & 63;
    const int wv   = threadIdx.x >> 6;        // 0 = GRU2 wave, 1 = GRU1/proj wave
    const int row  = blockIdx.x;
    const int l32  = lane & 31;
    const int* __restrict__ trow = tokens + row * TT;

    __shared__ float4 xb[4][64];              // ring of x-triples

    // 192 named weight scalars (roles: see LDA/LDB below)
    #define DECLW(k) float wz##k = 0.f, wr##k = 0.f, wh##k = 0.f;
    R64(DECLW)
    #undef DECLW

    float f0, f1, f2, f3 = 0.f, f4 = 0.f;     // role-dependent biases

    if (wv == 0) {
        // Wave A: wz_k/wr_k/wh_k = kh2 z/r/h column weights for k-th h2 unit
        #define LDA(k) wz##k = kh2[k * 192 + lane]; \
                       wr##k = kh2[k * 192 + 64 + lane]; \
                       wh##k = kh2[k * 192 + 128 + lane];
        R64(LDA)
        #undef LDA
        f0 = b2[192 + lane];                  // recurrent biases b2[1]
        f1 = b2[256 + lane];
        f2 = b2[320 + lane];
    } else {
        // Wave B (a=0..31, b=a+32):
        //   wz_a = kh1 z/r col (lane-split), wz_b = kh1 h col (lanes<32)
        //   wr_a/wr_b/wh_a = kx2 z/r/h cols
        #define LDB(a,b) wz##a = kh1[a * 96 + lane]; \
                         wz##b = (lane < 32) ? kh1[a * 96 + 64 + lane] : 0.f; \
                         wr##a = kx2[a * 192 + lane]; \
                         wr##b = kx2[a * 192 + 64 + lane]; \
                         wh##a = kx2[a * 192 + 128 + lane];
        R32P(LDB)
        #undef LDB
        f0 = b1[96 + lane];                   // GRU1 recurrent z/r bias
        f1 = (lane < 32) ? b1[160 + lane] : 0.f;   // GRU1 recurrent h bias
        f2 = b2[lane];                        // input-proj biases b2[0]
        f3 = b2[64 + lane];
        f4 = b2[128 + lane];
    }

    float h1 = 0.f, h2 = 0.f;
    float pz = 0.f, pr = 0.f, ph = 0.f;
    if (wv == 1) {                            // p-triple for GRU1 step 0
        const float* __restrict__ p = P1 + trow[0] * 96;
        pz = p[l32]; pr = p[32 + l32]; ph = p[64 + l32];
    }

    float mz, mr, mh;

    #pragma unroll 1
    for (int t = -1; t < TT; ++t) {
        // ---------------- pre-barrier ----------------
        if (wv == 0) {
            if (t >= 0) {
                mz = f0; mr = f1; mh = f2;
                #define AMV(k) { float s = rl(h2, k); \
                                 mz = fmaf(s, wz##k, mz); \
                                 mr = fmaf(s, wr##k, mr); \
                                 mh = fmaf(s, wh##k, mh); }
                R64(AMV)
                #undef AMV
            }
        } else if (t + 1 < TT) {
            // prefetch p(t+2)
            int t2 = (t + 2 < TT) ? (t + 2) : (TT - 1);
            const float* __restrict__ pn = P1 + trow[t2] * 96;
            float pzn = pn[l32], prn = pn[32 + l32], phn = pn[64 + l32];
            // GRU1 recurrence: h1(t) -> h1(t+1)
            float az = f0, ah = f1;
            #define BREC(a,b) { float s = rl(h1, a); \
                                az = fmaf(s, wz##a, az); \
                                ah = fmaf(s, wz##b, ah); }
            R32P(BREC)
            #undef BREC
            float ra  = __shfl_xor(az, 32);   // r-preact to lanes 0..31
            float z1  = sigmf(pz + az);
            float g1  = sigmf(pr + ra);
            float hh1 = tanhf_fast(ph + g1 * ah);
            h1 = z1 * h1 + (1.f - z1) * hh1;
            pz = pzn; pr = prn; ph = phn;
        }
        __syncthreads();
        // ---------------- post-barrier ----------------
        if (wv == 0) {
            if (t >= 0) {
                float4 x  = xb[t & 3][lane];
                float z2  = sigmf(x.x + mz);
                float r2  = sigmf(x.y + mr);
                float hh2 = tanhf_fast(x.z + r2 * mh);   // reset after recurrent mm
                h2 = z2 * h2 + (1.f - z2) * hh2;
            }
        } else if (t + 1 < TT) {
            // x(t+1) = h1(t+1)·kx2 + b2[0]  -> ring slot (t+1)&3
            float xz = f2, xr = f3, xh = f4;
            #define BPRJ(a,b) { float s = rl(h1, a); \
                                xz = fmaf(s, wr##a, xz); \
                                xr = fmaf(s, wr##b, xr); \
                                xh = fmaf(s, wh##a, xh); }
            R32P(BPRJ)
            #undef BPRJ
            xb[(t + 1) & 3][lane] = make_float4(xz, xr, xh, 0.f);
        }
    }

    // ---- tail: GLU + dense head, wave A only (holds h2) ----
    if (wv == 0) {
        float a0 = bg[lane], a1 = bg[64 + lane], a2 = bg[128 + lane], a3 = bg[192 + lane];
        #pragma unroll
        for (int k = 0; k < 64; ++k) {
            float s = rl(h2, k);
            a0 += s * wg[k * 256 + lane];
            a1 += s * wg[k * 256 + 64 + lane];
            a2 += s * wg[k * 256 + 128 + lane];
            a3 += s * wg[k * 256 + 192 + lane];
        }
        float g = a0 * sigmf(a2) * wd[lane] + a1 * sigmf(a3) * wd[64 + lane];
        g += __shfl_xor(g, 32); g += __shfl_xor(g, 16); g += __shfl_xor(g, 8);
        g += __shfl_xor(g, 4);  g += __shfl_xor(g, 2);  g += __shfl_xor(g, 1);
        if (lane == 0) out[row] = sigmf(g + bd[0]);
    }
}

extern "C" void kernel_launch(void* const* d_in, const int* in_sizes, int n_in,
                              void* d_out, int out_size, void* d_ws, size_t ws_size,
                              hipStream_t stream) {
    const int*   tokens = (const int*)d_in[0];
    const float* emb = (const float*)d_in[1];
    const float* kx1 = (const float*)d_in[2];
    const float* kh1 = (const float*)d_in[3];
    const float* b1  = (const float*)d_in[4];
    const float* kx2 = (const float*)d_in[5];
    const float* kh2 = (const float*)d_in[6];
    const float* b2  = (const float*)d_in[7];
    const float* wg  = (const float*)d_in[8];
    const float* bg  = (const float*)d_in[9];
    const float* wd  = (const float*)d_in[10];
    const float* bd  = (const float*)d_in[11];
    float* out = (float*)d_out;
    float* P1  = (float*)d_ws;   // needs 50257*96*4 = 19.3 MB of workspace

    proj_emb<<<(VV + 7) / 8, 96, 0, stream>>>(emb, kx1, b1, P1);
    rnn_main<<<BB, 128, 0, stream>>>(tokens, P1, kh1, b1, kx2, kh2, b2,
                                     wg, bg, wd, bd, out);
}